// Round 7
// baseline (88.341 us; speedup 1.0000x reference)
//
#include <hip/hip_runtime.h>

// LogisticRegressionRBF: out[k] = sigmoid( sum_n w[n]*exp(-||x_k - c_n||^2) + b )
// K=65536, N=4096, M=64. fp32 in/out.
//
// R14: de-convoy the main loop. R13 evidence: main ~30 us regardless of
// prefetch depth / VALU diet / geometry, vs ~12-15 us if MFMA (7.3),
// screen VALU (~9) and cb L2 reads (~7) overlapped. Diagnosis: all 16
// waves/CU run the SAME 1-phase loop in lockstep after __syncthreads ->
// MFMA bursts, VALU bursts and load bursts alternate chip-wide (sum, not
// max). Fixes:
//   1. per-wave chunk ROTATION: wave wv starts at chunk (wv*4)&31 (sum over
//      chunks is commutative) -> 8 waves sit at 8 different loop phases ->
//      cross-wave pipe interleave + spread L2 sectors. ~3 VALU/chunk extra.
//   2. s_setprio(1) around the MFMA pair (T5: pays only with role
//      diversity, which rotation now provides).
//   3. meta unpack hoisted before the MFMAs (off the result-dependent chain).
// Kept from R13: ring-3 register prefetch with literal slots, bf16-packed
// meta {tq|w}, 32-bit saddr addressing, one ballot/chunk, rare-hit LDS
// atomics. Reg ledger ~64 VGPR + 64 AGPR <= 128 cap (512,4). WRITE_SIZE
// ~0.5 MB is the spill tripwire.

#define KOBS 65536
#define NCENT 4096
#define MFEAT 64
#define NCHUNK 32                    // 4096 / 128 centers per chunk

#define SCALE_A 2.8853900817779268f  // 2*log2(e)
#define QS      1.4426950408889634f  // log2(e)
#define TSKIP   -60.0f

typedef __attribute__((ext_vector_type(4)))  float float4v;
typedef __attribute__((ext_vector_type(16))) float float16v;
typedef __attribute__((ext_vector_type(8)))  int   int8v;

#if __has_builtin(__builtin_amdgcn_exp2f)
#define EXP2F(x) __builtin_amdgcn_exp2f(x)
#else
#define EXP2F(x) exp2f(x)
#endif

static __device__ inline unsigned f2bfu(float f) {
    unsigned u = __float_as_uint(f);
    return (u + 0x7fffu + ((u >> 16) & 1u)) >> 16;
}

#define MFMA(A, B, C) __builtin_amdgcn_mfma_scale_f32_32x32x64_f8f6f4( \
    (A), (B), (C), 0, 0, 0, 0x7f7f7f7f, 0, 0x7f7f7f7f)

// ================================ prep =====================================
// Blocks [0,128): transpose+quantize xb fp32 -> fp8 e4m3 B-fragments.
// Blocks [128,1152): hcw[n] = { bf16(TSKIP + log2e*||c_n||^2) | bf16(w[n]) }.
__global__ __launch_bounds__(256) void rbf_prep(
    const float* __restrict__ xb, const float* __restrict__ w,
    char* __restrict__ cb, unsigned* __restrict__ hcw) {
    const int bid = blockIdx.x;
    const int tid = threadIdx.x;
    if (bid < 128) {
        const int o      = bid * 256 + tid;   // (center, k-octet), [0, 32768)
        const int col    = o >> 3;            // center index
        const int joct   = o & 7;             // k0 = joct*8
        const int c      = col >> 7;          // chunk
        const int w4     = (col >> 5) & 3;    // wave-quarter within chunk
        const int lanelo = col & 31;
        const int l      = lanelo + (joct >> 2) * 32;  // lane (k-half select)
        const int j0     = (joct & 3) * 8;             // byte offset in 32B
        const float* src = xb + col * MFEAT + joct * 8;
        float4v v0 = *(const float4v*)(src);
        float4v v1 = *(const float4v*)(src + 4);
        int lo = __builtin_amdgcn_cvt_pk_fp8_f32(v0[0], v0[1], 0, false);
        lo     = __builtin_amdgcn_cvt_pk_fp8_f32(v0[2], v0[3], lo, true);
        int hi = __builtin_amdgcn_cvt_pk_fp8_f32(v1[0], v1[1], 0, false);
        hi     = __builtin_amdgcn_cvt_pk_fp8_f32(v1[2], v1[3], hi, true);
        unsigned long long pk = (unsigned long long)(unsigned)lo |
                                ((unsigned long long)(unsigned)hi << 32);
        *(unsigned long long*)(cb + (size_t)((c * 4 + w4) * 64 + l) * 32 + j0) = pk;
    } else {
        const int row  = (bid - 128) * 4 + (tid >> 6);
        const int lane = tid & 63;
        float v = xb[row * MFEAT + lane];
        float s = v * v;
        #pragma unroll
        for (int off = 32; off > 0; off >>= 1) s += __shfl_xor(s, off, 64);
        if (lane == 0)
            hcw[row] = (f2bfu(TSKIP + QS * s) << 16) | f2bfu(w[row]);
    }
}

// ================================ main =====================================
// grid 512 x block 512. Block: 128 output rows.
// Wave wv: rt = wv>>2 row-tile (64 rows), wq = wv&3 center quarter.
__global__ __launch_bounds__(512, 4) void rbf_main(
    const float* __restrict__ x, const char* __restrict__ cb,
    const unsigned* __restrict__ hcw, const float* __restrict__ bptr,
    float* __restrict__ out) {
    __shared__ float x2s[128];
    __shared__ float zl[128];

    const int tid  = threadIdx.x;
    const int wv   = tid >> 6;
    const int lane = tid & 63;
    const int ll   = lane & 31;
    const int lh   = lane >> 5;
    const int rt   = wv >> 2;
    const int wq   = wv & 3;
    const int bid  = (int)blockIdx.x;

    if (tid < 128) zl[tid] = 0.0f;

    // ---- A fragments (fp8, pre-scaled by 2*log2e) + row norms ----
    // A-frag layout 32x32x64: lane l holds row l&31, k = (l>>5)*32 + byte.
    const int r0e = bid * 128 + rt * 64;
    int8v af0, af1;
    #pragma unroll
    for (int t = 0; t < 2; ++t) {
        const float* xr = x + (size_t)(r0e + t * 32 + ll) * MFEAT + lh * 32;
        int8v a;
        float ss = 0.0f;
        #pragma unroll
        for (int rg = 0; rg < 8; ++rg) {
            float4v v = *(const float4v*)(xr + rg * 4);
            ss = fmaf(v[0], v[0], ss); ss = fmaf(v[1], v[1], ss);
            ss = fmaf(v[2], v[2], ss); ss = fmaf(v[3], v[3], ss);
            int pk = __builtin_amdgcn_cvt_pk_fp8_f32(
                SCALE_A * v[0], SCALE_A * v[1], 0, false);
            pk = __builtin_amdgcn_cvt_pk_fp8_f32(
                SCALE_A * v[2], SCALE_A * v[3], pk, true);
            a[rg] = pk;
        }
        ss += __shfl_xor(ss, 32, 64);   // partner lane has other k-half
        if (t == 0) af0 = a; else af1 = a;
        if (wq == 0 && lh == 0) x2s[rt * 64 + t * 32 + ll] = ss;
    }
    __syncthreads();

    // ---- C-init: p = -log2e*||x_row||^2 in C/D layout ----
    // row = (reg&3) + 8*(reg>>2) + 4*(lane>>5)  [+ t*32]
    const int rb = 4 * lh;
    float16v p0, p1;
    #pragma unroll
    for (int i = 0; i < 16; ++i) {
        const int ri = rb + (i & 3) + 8 * (i >> 2);
        p0[i] = -QS * x2s[rt * 64 + ri];
        p1[i] = -QS * x2s[rt * 64 + 32 + ri];
    }

    // ---- main loop: rotated chunk order + ring-3 register prefetch ----
    const int zbase = rt * 64 + rb;
    const unsigned cboff = (unsigned)(wq * 64 + lane) * 32u;  // voffset, saddr
    const unsigned moff  = (unsigned)(wq * 32 + ll);
    const int base = (wv * 4) & 31;   // per-wave chunk rotation (de-convoy)

    int8v    pb[3];
    unsigned mw[3];

    #define LOADB(C, S) do {                                               \
        pb[S] = *(const int8v*)(cb + cboff + (unsigned)(C) * 8192u);       \
        mw[S] = hcw[moff + (unsigned)(C) * 128u];                          \
    } while (0)

    #define STEP(SCUR, SPRE, CPRE, DOLOAD) do {                            \
        const unsigned mu = mw[SCUR];                                      \
        const float tq  = __uint_as_float(mu & 0xffff0000u);               \
        const float wv_ = __uint_as_float(mu << 16);                       \
        if (DOLOAD) LOADB(CPRE, SPRE);                                     \
        __builtin_amdgcn_s_setprio(1);                                     \
        float16v a0 = MFMA(af0, pb[SCUR], p0);                             \
        float16v a1 = MFMA(af1, pb[SCUR], p1);                             \
        __builtin_amdgcn_s_setprio(0);                                     \
        float uA0 = fmaxf(fmaxf(a0[0],  a0[1]),  a0[2]);                   \
        float uA1 = fmaxf(fmaxf(a0[3],  a0[4]),  a0[5]);                   \
        float uA2 = fmaxf(fmaxf(a0[6],  a0[7]),  a0[8]);                   \
        float uA3 = fmaxf(fmaxf(a0[9],  a0[10]), a0[11]);                  \
        float uA4 = fmaxf(fmaxf(a0[12], a0[13]), a0[14]);                  \
        float mA  = fmaxf(fmaxf(fmaxf(uA0, uA1), uA2),                     \
                          fmaxf(fmaxf(uA3, uA4), a0[15]));                 \
        float uB0 = fmaxf(fmaxf(a1[0],  a1[1]),  a1[2]);                   \
        float uB1 = fmaxf(fmaxf(a1[3],  a1[4]),  a1[5]);                   \
        float uB2 = fmaxf(fmaxf(a1[6],  a1[7]),  a1[8]);                   \
        float uB3 = fmaxf(fmaxf(a1[9],  a1[10]), a1[11]);                  \
        float uB4 = fmaxf(fmaxf(a1[12], a1[13]), a1[14]);                  \
        float mB  = fmaxf(fmaxf(fmaxf(uB0, uB1), uB2),                     \
                          fmaxf(fmaxf(uB3, uB4), a1[15]));                 \
        if (__any(fmaxf(mA, mB) > tq)) {       /* one ballot per chunk */  \
            const float q = TSKIP - tq;        /* = -log2e*||c||^2 */      \
            if (mA > tq) {                                                 \
                _Pragma("unroll")                                          \
                for (int i_ = 0; i_ < 16; ++i_)                            \
                    atomicAdd(&zl[zbase + (i_ & 3) + 8 * (i_ >> 2)],       \
                              wv_ * EXP2F(a0[i_] + q));                    \
            }                                                              \
            if (mB > tq) {                                                 \
                _Pragma("unroll")                                          \
                for (int i_ = 0; i_ < 16; ++i_)                            \
                    atomicAdd(&zl[zbase + 32 + (i_ & 3) + 8 * (i_ >> 2)],  \
                              wv_ * EXP2F(a1[i_] + q));                    \
            }                                                              \
        }                                                                  \
    } while (0)

    LOADB(base, 0);
    LOADB((base + 1) & 31, 1);

    #pragma unroll 1
    for (int i = 0; i < 30; i += 3) {    // rotated chunks; slot = i % 3
        STEP(0, 2, (base + i + 2) & 31, 1);
        STEP(1, 0, (base + i + 3) & 31, 1);
        STEP(2, 1, (base + i + 4) & 31, 1);
    }
    STEP(0, 2, 0, 0);                    // peeled, no prefetch
    STEP(1, 0, 0, 0);

    #undef STEP
    #undef LOADB

    // ---- combine, sigmoid, store ----
    __syncthreads();
    if (tid < 128) {
        const float z = zl[tid] + bptr[0];
        out[bid * 128 + tid] = 1.0f / (1.0f + EXP2F(-QS * z));
    }
}

// ================================ launcher =================================
extern "C" void kernel_launch(void* const* d_in, const int* in_sizes, int n_in,
                              void* d_out, int out_size, void* d_ws, size_t ws_size,
                              hipStream_t stream) {
    const float* x  = (const float*)d_in[0];   // [K, M]
    const float* xb = (const float*)d_in[1];   // [N, M]
    const float* w  = (const float*)d_in[2];   // [1, N]
    const float* b  = (const float*)d_in[3];   // [1]
    float* out = (float*)d_out;                // [K]

    char*     cb  = (char*)d_ws;                               // 256 KB fp8
    unsigned* hcw = (unsigned*)((char*)d_ws + NCENT * MFEAT);  // 16 KB packed meta

    rbf_prep<<<128 + NCENT / 4, 256, 0, stream>>>(xb, w, cb, hcw);
    rbf_main<<<KOBS / 128, 512, 0, stream>>>(x, cb, hcw, b, out);
}